// Round 7
// baseline (721.249 us; speedup 1.0000x reference)
//
#include <hip/hip_runtime.h>

// WTConv2d: 3-level Haar DWT -> 5x5 conv (256ch) per level -> IDWT pyramid + bias.
// Convs: 256x256 implicit GEMM, 4 quadrant-phases/K-tile, full-lead ds_read pipelining,
// counted lgkm gates, K-split (bf16 partials). DWT/IDWT: LDS-transposed coalesced kernels;
// IDWT fuses the K-split partial reduction.
// NOTE: s1/s2 border zeroing MUST run after conv0 (dwtT0 writes the whole S0 region).

typedef unsigned short u16;
typedef __attribute__((ext_vector_type(8))) __bf16 bf16x8;
typedef __attribute__((ext_vector_type(8))) unsigned short us8;
typedef __attribute__((ext_vector_type(4))) float f32x4;

__device__ __forceinline__ u16 f2bf(float f) {
  union { float f; unsigned u; } v; v.f = f;
  unsigned r = v.u + 0x7fffu + ((v.u >> 16) & 1u);   // RNE
  return (u16)(r >> 16);
}
__device__ __forceinline__ float bf2f(u16 u) {
  union { unsigned u; float f; } v; v.u = ((unsigned)u) << 16;
  return v.f;
}

typedef const unsigned int __attribute__((address_space(1)))* gas1_t;
typedef unsigned int __attribute__((address_space(3)))* gas3_t;
__device__ __forceinline__ void gload16(const void* g, void* l) {
  __builtin_amdgcn_global_load_lds((gas1_t)g, (gas3_t)l, 16, 0, 0);
}

// ---------------- weight transform x3: OIHW fp32 -> [tap][co][ci] bf16 ----------------
__global__ void k_wtrans3(const float* __restrict__ wa, const float* __restrict__ wb_,
                          const float* __restrict__ wc, u16* __restrict__ oa,
                          u16* __restrict__ ob, u16* __restrict__ oc) {
  const float* w = (blockIdx.y == 0) ? wa : (blockIdx.y == 1) ? wb_ : wc;
  u16* o = (blockIdx.y == 0) ? oa : (blockIdx.y == 1) ? ob : oc;
  int co = blockIdx.x;
  int ci = threadIdx.x;
  const float* src = w + ((long)co * 256 + ci) * 25;
  float v[25];
#pragma unroll
  for (int tp = 0; tp < 25; ++tp) v[tp] = src[tp];
#pragma unroll
  for (int tp = 0; tp < 25; ++tp)
    o[((long)tp * 256 + co) * 256 + ci] = f2bf(v[tp]);
}

// ---------------- border zero (pad frame of stacked buffer) ----------------
__global__ void k_border(u16* __restrict__ st, int B_, int H2, int W2) {
  int PW = W2 + 4;
  int npix = 4 * PW + 4 * H2;
  int gid = blockIdx.x * blockDim.x + threadIdx.x;
  int pid = gid >> 6, lane = gid & 63;
  if (pid >= B_ * npix) return;
  int b = pid / npix, p = pid % npix;
  int row, col;
  if (p < 2 * PW) { row = p / PW; col = p % PW; }
  else if (p < 4 * PW) { int q = p - 2 * PW; row = H2 + 2 + q / PW; col = q % PW; }
  else { int q = p - 4 * PW; row = 2 + (q >> 2); int c4 = q & 3; col = (c4 < 2) ? c4 : W2 + c4; }
  long base = (((long)b * (H2 + 4) + row) * PW + col) * 256 + lane * 4;
  *(ushort4*)(st + base) = make_ushort4(0, 0, 0, 0);
}

// ---------------- transposed DWT: fp32 NCHW -> padded NHWC bf16 (coalesced) + ll fp32 ----
// One block per (b, h2, chunk of NCOLS output cols). Compute -> LDS (span-linear) -> copy.
template <int NCOLS>
__global__ __launch_bounds__(256) void k_dwtT(const float* __restrict__ in,
                                              u16* __restrict__ st, float* __restrict__ ll,
                                              int B_, int H2, int W2, int nch) {
  __shared__ u16 lds16[NCOLS * 256];
  int blk = blockIdx.x;
  int cw = blk % nch; int rest = blk / nch;
  int h2 = rest % H2; int b = rest / H2;
  int t = threadIdx.x;
  int c = t >> 2, g = t & 3;
  constexpr int NC4 = NCOLS / 4;      // cols per g-group (16 or 8)
  constexpr int NPAIR = NC4 / 2;

  const float* r0 = in + (((long)(b * 64 + c) * (2 * H2) + 2 * h2) * (2 * W2)) + 2 * (cw * NCOLS + g * NC4);
  const float* r1 = r0 + 2 * W2;
  float llv[NC4];
#pragma unroll
  for (int j = 0; j < NPAIR; ++j) {
    float4 tp = *(const float4*)(r0 + 4 * j);
    float4 bt = *(const float4*)(r1 + 4 * j);
    float ll0 = 0.5f * (tp.x + tp.y + bt.x + bt.y);
    float lh0 = 0.5f * (tp.x + tp.y - bt.x - bt.y);
    float hl0 = 0.5f * (tp.x - tp.y + bt.x - bt.y);
    float hh0 = 0.5f * (tp.x - tp.y - bt.x + bt.y);
    float ll1 = 0.5f * (tp.z + tp.w + bt.z + bt.w);
    float lh1 = 0.5f * (tp.z + tp.w - bt.z - bt.w);
    float hl1 = 0.5f * (tp.z - tp.w + bt.z - bt.w);
    float hh1 = 0.5f * (tp.z - tp.w - bt.z + bt.w);
    int w = g * NC4 + 2 * j;
    *(ushort4*)(lds16 + w * 256 + 4 * c)       = make_ushort4(f2bf(ll0), f2bf(lh0), f2bf(hl0), f2bf(hh0));
    *(ushort4*)(lds16 + (w + 1) * 256 + 4 * c) = make_ushort4(f2bf(ll1), f2bf(lh1), f2bf(hl1), f2bf(hh1));
    llv[2 * j] = ll0; llv[2 * j + 1] = ll1;
  }
  float* lp = ll + (((long)(b * 64 + c) * H2 + h2) * W2 + cw * NCOLS + g * NC4);
#pragma unroll
  for (int j = 0; j < NC4; j += 4)
    *(float4*)(lp + j) = make_float4(llv[j], llv[j + 1], llv[j + 2], llv[j + 3]);
  __syncthreads();
  u16* dst = st + (((long)b * (H2 + 4) + (h2 + 2)) * (W2 + 4) + 2 + cw * NCOLS) * 256;
  constexpr int NVEC = NCOLS / 8;
#pragma unroll
  for (int i = 0; i < NVEC; ++i) {
    int eo = (i * 256 + t) * 8;
    *(us8*)(dst + eo) = *(const us8*)(lds16 + eo);
  }
}

// ---------------- 256x256 conv, full-lead cross-phase pipelining ----------------
__global__ __launch_bounds__(512, 2) void k_conv8(
    const u16* __restrict__ st, const u16* __restrict__ wt, u16* __restrict__ out,
    int H2, int W2, int ktot, int nsplit) {
  __shared__ __align__(16) char smem[131072];   // 2 bufs x (A 32K + B 32K)
  const int t = threadIdx.x;
  const int lane = t & 63;
  const int wv = t >> 6;
  const int wm = wv >> 2, wn = wv & 3;          // 2M x 4N waves; wave tile 128x64
  const int nwg = gridDim.x;
  const int bid = blockIdx.x;
  const int lb = (bid & 7) * (nwg >> 3) + (bid >> 3);  // XCD-chunked (nwg%8==0)
  const int m0 = lb * 256;
  const int PW = W2 + 4;
  const int spl = blockIdx.y;
  const int kk0 = (spl * ktot) / nsplit;
  const int kk1 = ((spl + 1) * ktot) / nsplit;
  const long Mrows = (long)nwg * 256;
  u16* yo = out + (long)spl * Mrows * 256;

  const int trow = t >> 3;
  const int srcci = ((t & 7) ^ (trow & 7)) * 8;
  const char* baseA[4];
#pragma unroll
  for (int u = 0; u < 4; ++u) {
    int m = m0 + u * 64 + trow;
    int w = m % W2; int q = m / W2;
    int hh = q % H2; int b = q / H2;
    long sp = ((long)(b * (H2 + 4) + hh + 2) * PW + (w + 2));
    baseA[u] = (const char*)(st + sp * 256 + srcci);
  }
  const char* baseB0 = (const char*)(wt + trow * 256 + srcci);

  f32x4 acc[8][4];
#pragma unroll
  for (int i = 0; i < 8; ++i)
#pragma unroll
    for (int j = 0; j < 4; ++j) acc[i][j] = f32x4{0.f, 0.f, 0.f, 0.f};

  const int kq = (lane >> 4) * 16;
  const int sw = (lane & 7) << 4;
  int va0 = (wm * 128 + (lane & 15)) * 128 + (kq ^ sw);
  int va1 = (wm * 128 + (lane & 15)) * 128 + ((64 + kq) ^ sw);
  int vb0 = 32768 + (wn * 64 + (lane & 15)) * 128 + (kq ^ sw);
  int vb1 = 32768 + (wn * 64 + (lane & 15)) * 128 + ((64 + kq) ^ sw);

  bf16x8 a0[4][2], a1[4][2], b0[2][2], b1[2][2];

  auto offsets = [&](int kk, long& oA, long& oB) {
    int tap = kk >> 2, cic = kk & 3;
    int dy = tap / 5 - 2, dx = tap % 5 - 2;
    oA = ((long)(dy * PW + dx) * 256 + cic * 64) * 2;
    oB = ((long)tap * 65536 + cic * 64) * 2;
  };
  auto stageA4 = [&](long off, int dsto) {
    char* d = smem + dsto + wv * 1024;
#pragma unroll
    for (int u = 0; u < 4; ++u) gload16(baseA[u] + off, d + u * 8192);
  };
  auto stageB4 = [&](long off, int dsto) {
    char* d = smem + dsto + 32768 + wv * 1024;
#pragma unroll
    for (int u = 0; u < 4; ++u) gload16(baseB0 + u * 32768 + off, d + u * 8192);
  };

#define LDA0 { _Pragma("unroll") for (int i = 0; i < 4; ++i) {       \
    a0[i][0] = *(const bf16x8*)(smem + va0 + i * 2048);              \
    a0[i][1] = *(const bf16x8*)(smem + va1 + i * 2048); } }
#define LDA1 { _Pragma("unroll") for (int i = 0; i < 4; ++i) {       \
    a1[i][0] = *(const bf16x8*)(smem + va0 + 8192 + i * 2048);       \
    a1[i][1] = *(const bf16x8*)(smem + va1 + 8192 + i * 2048); } }
#define LDB0 { _Pragma("unroll") for (int j = 0; j < 2; ++j) {       \
    b0[j][0] = *(const bf16x8*)(smem + vb0 + j * 2048);              \
    b0[j][1] = *(const bf16x8*)(smem + vb1 + j * 2048); } }
#define LDB1 { _Pragma("unroll") for (int j = 0; j < 2; ++j) {       \
    b1[j][0] = *(const bf16x8*)(smem + vb0 + 4096 + j * 2048);       \
    b1[j][1] = *(const bf16x8*)(smem + vb1 + 4096 + j * 2048); } }
#define MMQ(A, B, IB, JB)                                                     \
  _Pragma("unroll") for (int i = 0; i < 4; ++i)                               \
  _Pragma("unroll") for (int j = 0; j < 2; ++j)                               \
  _Pragma("unroll") for (int k = 0; k < 2; ++k)                               \
    acc[(IB) + i][(JB) + j] = __builtin_amdgcn_mfma_f32_16x16x32_bf16(        \
        A[i][k], B[j][k], acc[(IB) + i][(JB) + j], 0, 0, 0);

  long oA, oB;
  offsets(kk0, oA, oB);
  stageA4(oA, 0); stageB4(oB, 0);
  offsets(kk0 + 1, oA, oB);
  stageA4(oA, 65536); stageB4(oB, 65536);
  asm volatile("s_waitcnt vmcnt(8)" ::: "memory");
  __builtin_amdgcn_s_barrier();
  LDA0 LDB0

  int curo = 0;
  for (int kt = kk0; kt < kk1; ++kt) {
    const bool stg = (kt + 2) < kk1;
    const bool rd1 = (kt + 1) < kk1;
    LDA1 LDB1
    va0 ^= 65536; va1 ^= 65536; vb0 ^= 65536; vb1 ^= 65536;
    __builtin_amdgcn_s_barrier();
    asm volatile("s_waitcnt lgkmcnt(12)" ::: "memory");
    __builtin_amdgcn_sched_barrier(0);
    __builtin_amdgcn_s_setprio(1);
    MMQ(a0, b0, 0, 0)
    __builtin_amdgcn_s_setprio(0);
    __builtin_amdgcn_s_barrier();
    asm volatile("s_waitcnt lgkmcnt(4)" ::: "memory");
    __builtin_amdgcn_sched_barrier(0);
    __builtin_amdgcn_s_setprio(1);
    MMQ(a1, b0, 4, 0)
    __builtin_amdgcn_s_setprio(0);
    if (rd1) { asm volatile("s_waitcnt vmcnt(0)" ::: "memory"); }
    __builtin_amdgcn_s_barrier();
    asm volatile("s_waitcnt lgkmcnt(0)" ::: "memory");
    __builtin_amdgcn_sched_barrier(0);
    __builtin_amdgcn_s_setprio(1);
    MMQ(a1, b1, 4, 2)
    __builtin_amdgcn_s_setprio(0);
    if (rd1) { LDB0 }
    if (stg) { offsets(kt + 2, oA, oB); stageA4(oA, curo); }
    __builtin_amdgcn_s_barrier();
    __builtin_amdgcn_s_setprio(1);
    MMQ(a0, b1, 0, 2)
    __builtin_amdgcn_s_setprio(0);
    if (stg) { stageB4(oB, curo); }
    if (rd1) { LDA0 }
    curo ^= 65536;
  }
#undef MMQ
#undef LDA0
#undef LDA1
#undef LDB0
#undef LDB1

#pragma unroll
  for (int i = 0; i < 8; ++i) {
    int mloc = m0 + wm * 128 + i * 16 + (lane >> 4) * 4;
#pragma unroll
    for (int j = 0; j < 4; ++j) {
      int nloc = wn * 64 + j * 16 + (lane & 15);
#pragma unroll
      for (int r = 0; r < 4; ++r)
        yo[(long)(mloc + r) * 256 + nloc] = f2bf(acc[i][j][r]);
    }
  }
}

// ---------------- transposed IDWT + fused K-split reduce ----------------
// P: ns partials, each [B,H2,W2,256] bf16 span-linear; out fp32 NCHW [B,64,2H2,2W2].
template <int NCOLS>
__global__ __launch_bounds__(256) void k_idwtT(const u16* __restrict__ P, long psz, int ns,
                                               const float* __restrict__ nll,
                                               const float* __restrict__ bias,
                                               float* __restrict__ out,
                                               int B_, int H2, int W2, int nch) {
  __shared__ u16 lds16[NCOLS * 256];
  int blk = blockIdx.x;
  int cw = blk % nch; int rest = blk / nch;
  int h2 = rest % H2; int b = rest / H2;
  int t = threadIdx.x;
  long span = (((long)b * H2 + h2) * W2 + cw * NCOLS) * 256;
  constexpr int NVEC = NCOLS / 8;
#pragma unroll
  for (int i = 0; i < NVEC; ++i) {
    int eo = (i * 256 + t) * 8;
    float s[8] = {0.f, 0.f, 0.f, 0.f, 0.f, 0.f, 0.f, 0.f};
    for (int k = 0; k < ns; ++k) {
      us8 v = *(const us8*)(P + (long)k * psz + span + eo);
#pragma unroll
      for (int e = 0; e < 8; ++e) s[e] += bf2f(v[e]);
    }
    us8 o;
#pragma unroll
    for (int e = 0; e < 8; ++e) o[e] = f2bf(s[e]);
    *(us8*)(lds16 + eo) = o;
  }
  __syncthreads();
  int c = t >> 2, g = t & 3;
  constexpr int NC4 = NCOLS / 4;
  float bv = bias ? bias[c] : 0.f;
  const float* np = nll ? (nll + (((long)(b * 64 + c) * H2 + h2) * W2 + cw * NCOLS)) : nullptr;
  float* r0 = out + (((long)(b * 64 + c) * (2 * H2) + 2 * h2) * (2 * W2)) + 2 * (cw * NCOLS);
  float* r1 = r0 + 2 * W2;
#pragma unroll
  for (int j = 0; j < NC4; j += 2) {
    int w = g * NC4 + j;
    ushort4 q0 = *(const ushort4*)(lds16 + w * 256 + 4 * c);
    ushort4 q1 = *(const ushort4*)(lds16 + (w + 1) * 256 + 4 * c);
    float llv0 = bf2f(q0.x), lh0 = bf2f(q0.y), hl0 = bf2f(q0.z), hh0 = bf2f(q0.w);
    float llv1 = bf2f(q1.x), lh1 = bf2f(q1.y), hl1 = bf2f(q1.z), hh1 = bf2f(q1.w);
    if (np) { llv0 += np[w]; llv1 += np[w + 1]; }
    float a0 = 0.5f * (llv0 + lh0 + hl0 + hh0) + bv;
    float b0 = 0.5f * (llv0 + lh0 - hl0 - hh0) + bv;
    float c0 = 0.5f * (llv0 - lh0 + hl0 - hh0) + bv;
    float d0 = 0.5f * (llv0 - lh0 - hl0 + hh0) + bv;
    float a1 = 0.5f * (llv1 + lh1 + hl1 + hh1) + bv;
    float b1 = 0.5f * (llv1 + lh1 - hl1 - hh1) + bv;
    float c1 = 0.5f * (llv1 - lh1 + hl1 - hh1) + bv;
    float d1 = 0.5f * (llv1 - lh1 - hl1 + hh1) + bv;
    *(float4*)(r0 + 2 * w) = make_float4(a0, b0, a1, b1);
    *(float4*)(r1 + 2 * w) = make_float4(c0, d0, c1, d1);
  }
}

// ---------------- workspace layout (bytes) ----------------
constexpr size_t WBF_SZ1 = 25ull * 256 * 256 * 2;             // 3,276,800
constexpr size_t OFF_WBF = 0;
constexpr size_t OFF_S0  = 3 * WBF_SZ1;                       // 9,830,400
constexpr size_t S0_SZ   = 8ull * 132 * 132 * 256 * 2;        // 71,368,704
constexpr size_t OFF_L0  = OFF_S0 + S0_SZ;                    // 81,199,104 (l0 33.5MB; later P1)
constexpr size_t OFF_Y0  = OFF_L0 + 8ull * 64 * 128 * 128 * 4;// 114,753,536 (y0 67MB)
// inside S0 (per-dispatch read/write sets verified disjoint; s1/s2 borders zeroed AFTER conv0):
constexpr size_t REL_S1 = 0;                                  // s1 19.0MB (dwt1->conv1)
constexpr size_t REL_L1 = 8ull * 68 * 68 * 256 * 2;           // 18,939,904: l1 8.4MB (dwt1->dwt2)
constexpr size_t REL_S2 = REL_L1 + 8ull * 64 * 64 * 64 * 4;   // 27,328,512: s2 5.3MB (dwt2->conv2)
constexpr size_t REL_P2 = REL_S2 + 8ull * 36 * 36 * 256 * 2;  // 32,636,928: P2 33.5MB (conv2->idwt2)
constexpr size_t REL_N2 = 0;                                  // n2 8.4MB (idwt2->idwt1); over dead s1
constexpr size_t REL_N1 = 8ull * 64 * 64 * 64 * 4;            // 8,388,608: n1 33.5MB (idwt1->idwt0)
constexpr size_t REL_L2 = 0;                                  // l2 8.4MB scratch (never read; over dead s1)

extern "C" void kernel_launch(void* const* d_in, const int* in_sizes, int n_in,
                              void* d_out, int out_size, void* d_ws, size_t ws_size,
                              hipStream_t stream) {
  const float* x    = (const float*)d_in[0];
  const float* w0   = (const float*)d_in[1];
  const float* w1   = (const float*)d_in[2];
  const float* w2   = (const float*)d_in[3];
  const float* bias = (const float*)d_in[4];
  float* out = (float*)d_out;
  char* ws = (char*)d_ws;

  u16* wbf0 = (u16*)(ws + OFF_WBF);
  u16* wbf1 = (u16*)(ws + OFF_WBF + WBF_SZ1);
  u16* wbf2 = (u16*)(ws + OFF_WBF + 2 * WBF_SZ1);
  u16* s0   = (u16*)(ws + OFF_S0);
  u16* s1   = (u16*)(ws + OFF_S0 + REL_S1);
  float* l1 = (float*)(ws + OFF_S0 + REL_L1);
  u16* s2   = (u16*)(ws + OFF_S0 + REL_S2);
  u16* P2   = (u16*)(ws + OFF_S0 + REL_P2);
  float* n2 = (float*)(ws + OFF_S0 + REL_N2);
  float* n1 = (float*)(ws + OFF_S0 + REL_N1);
  float* l2 = (float*)(ws + OFF_S0 + REL_L2);
  float* l0 = (float*)(ws + OFF_L0);
  u16* P1   = (u16*)(ws + OFF_L0);     // aliases l0 (dead after dwt1)
  u16* y0   = (u16*)(ws + OFF_Y0);

  k_wtrans3<<<dim3(256, 3), 256, 0, stream>>>(w0, w1, w2, wbf0, wbf1, wbf2);

  // level 0 (s0 border first; dwtT writes interior only)
  k_border<<<2080, 256, 0, stream>>>(s0, 8, 128, 128);
  k_dwtT<64><<<2048, 256, 0, stream>>>(x, s0, l0, 8, 128, 128, 2);
  k_conv8<<<dim3(512, 1), 512, 0, stream>>>(s0, wbf0, y0, 128, 128, 100, 1);

  // s1/s2 borders AFTER conv0 — dwtT0 wrote the whole S0 region (incl. these sub-buffers)
  k_border<<<1056, 256, 0, stream>>>(s1, 8, 64, 64);
  k_border<<<544, 256, 0, stream>>>(s2, 8, 32, 32);

  // level 1 (K-split 2 -> P1)
  k_dwtT<64><<<512, 256, 0, stream>>>(l0, s1, l1, 8, 64, 64, 1);
  k_conv8<<<dim3(128, 2), 512, 0, stream>>>(s1, wbf1, P1, 64, 64, 100, 2);

  // level 2 (K-split 8 -> P2)
  k_dwtT<32><<<256, 256, 0, stream>>>(l1, s2, l2, 8, 32, 32, 1);
  k_conv8<<<dim3(32, 8), 512, 0, stream>>>(s2, wbf2, P2, 32, 32, 100, 8);

  // reconstruction (idwt fuses partial reduce)
  k_idwtT<32><<<256, 256, 0, stream>>>(P2, 2097152L, 8, nullptr, nullptr, n2, 8, 32, 32, 1);
  k_idwtT<64><<<512, 256, 0, stream>>>(P1, 8388608L, 2, n2, nullptr, n1, 8, 64, 64, 1);
  k_idwtT<64><<<2048, 256, 0, stream>>>(y0, 33554432L, 1, n1, bias, out, 8, 128, 128, 2);
}

// Round 8
// 636.604 us; speedup vs baseline: 1.1330x; 1.1330x over previous
//
#include <hip/hip_runtime.h>

// WTConv2d: 3-level Haar DWT -> 5x5 conv (256ch) per level -> IDWT pyramid + bias.
// Convs: 256x256 implicit GEMM, 4 quadrant-phases/K-tile, full-lead ds_read pipelining,
// counted lgkm gates, K-split (bf16 partials). DWT/IDWT: round-5 scatter kernels
// (dense 8B scatter through L2 is fine; LDS-transpose variants measured SLOWER).
// k_idwt fuses the K-split partial reduction (no k_red, no y1/y2 buffers).
// NOTE: s1/s2 border zeroing MUST run after conv0 (dwt0 writes the whole S0 region).

typedef unsigned short u16;
typedef __attribute__((ext_vector_type(8))) __bf16 bf16x8;
typedef __attribute__((ext_vector_type(4))) float f32x4;

__device__ __forceinline__ u16 f2bf(float f) {
  union { float f; unsigned u; } v; v.f = f;
  unsigned r = v.u + 0x7fffu + ((v.u >> 16) & 1u);   // RNE
  return (u16)(r >> 16);
}
__device__ __forceinline__ float bf2f(u16 u) {
  union { unsigned u; float f; } v; v.u = ((unsigned)u) << 16;
  return v.f;
}

typedef const unsigned int __attribute__((address_space(1)))* gas1_t;
typedef unsigned int __attribute__((address_space(3)))* gas3_t;
__device__ __forceinline__ void gload16(const void* g, void* l) {
  __builtin_amdgcn_global_load_lds((gas1_t)g, (gas3_t)l, 16, 0, 0);
}

// ---------------- weight transform x3: OIHW fp32 -> [tap][co][ci] bf16 ----------------
__global__ void k_wtrans3(const float* __restrict__ wa, const float* __restrict__ wb_,
                          const float* __restrict__ wc, u16* __restrict__ oa,
                          u16* __restrict__ ob, u16* __restrict__ oc) {
  const float* w = (blockIdx.y == 0) ? wa : (blockIdx.y == 1) ? wb_ : wc;
  u16* o = (blockIdx.y == 0) ? oa : (blockIdx.y == 1) ? ob : oc;
  int co = blockIdx.x;
  int ci = threadIdx.x;
  const float* src = w + ((long)co * 256 + ci) * 25;
  float v[25];
#pragma unroll
  for (int tp = 0; tp < 25; ++tp) v[tp] = src[tp];
#pragma unroll
  for (int tp = 0; tp < 25; ++tp)
    o[((long)tp * 256 + co) * 256 + ci] = f2bf(v[tp]);
}

// ---------------- border zero (pad frame of stacked buffer) ----------------
__global__ void k_border(u16* __restrict__ st, int B_, int H2, int W2) {
  int PW = W2 + 4;
  int npix = 4 * PW + 4 * H2;
  int gid = blockIdx.x * blockDim.x + threadIdx.x;
  int pid = gid >> 6, lane = gid & 63;
  if (pid >= B_ * npix) return;
  int b = pid / npix, p = pid % npix;
  int row, col;
  if (p < 2 * PW) { row = p / PW; col = p % PW; }
  else if (p < 4 * PW) { int q = p - 2 * PW; row = H2 + 2 + q / PW; col = q % PW; }
  else { int q = p - 4 * PW; row = 2 + (q >> 2); int c4 = q & 3; col = (c4 < 2) ? c4 : W2 + c4; }
  long base = (((long)b * (H2 + 4) + row) * PW + col) * 256 + lane * 4;
  *(ushort4*)(st + base) = make_ushort4(0, 0, 0, 0);
}

// ---------------- DWT: fp32 NCHW -> stacked bf16 padded NHWC + ll fp32 ----------------
__global__ void k_dwt(const float* __restrict__ in, u16* __restrict__ st,
                      float* __restrict__ ll, int B_, int H2, int W2) {
  int idx = blockIdx.x * blockDim.x + threadIdx.x;
  int W2h = W2 >> 1;
  int total = B_ * 64 * H2 * W2h;
  if (idx >= total) return;
  int w2h = idx % W2h; int t2 = idx / W2h;
  int h2 = t2 % H2; t2 /= H2;
  int c = t2 % 64; int b = t2 / 64;
  int w2 = w2h * 2;
  const float* r0 = in + (((long)(b * 64 + c) * (2 * H2) + 2 * h2) * (2 * W2)) + 2 * w2;
  const float* r1 = r0 + 2 * W2;
  float4 tp = *(const float4*)r0;
  float4 bt = *(const float4*)r1;
  float ll0 = 0.5f * (tp.x + tp.y + bt.x + bt.y);
  float lh0 = 0.5f * (tp.x + tp.y - bt.x - bt.y);
  float hl0 = 0.5f * (tp.x - tp.y + bt.x - bt.y);
  float hh0 = 0.5f * (tp.x - tp.y - bt.x + bt.y);
  float ll1 = 0.5f * (tp.z + tp.w + bt.z + bt.w);
  float lh1 = 0.5f * (tp.z + tp.w - bt.z - bt.w);
  float hl1 = 0.5f * (tp.z - tp.w + bt.z - bt.w);
  float hh1 = 0.5f * (tp.z - tp.w - bt.z + bt.w);
  long sbase = (((long)b * (H2 + 4) + (h2 + 2)) * (W2 + 4) + (w2 + 2)) * 256 + 4 * c;
  *(ushort4*)(st + sbase)       = make_ushort4(f2bf(ll0), f2bf(lh0), f2bf(hl0), f2bf(hh0));
  *(ushort4*)(st + sbase + 256) = make_ushort4(f2bf(ll1), f2bf(lh1), f2bf(hl1), f2bf(hh1));
  long lbase = (((long)(b * 64 + c) * H2) + h2) * W2 + w2;
  *(float2*)(ll + lbase) = make_float2(ll0, ll1);
}

// ---------------- 256x256 conv, full-lead cross-phase pipelining ----------------
__global__ __launch_bounds__(512, 2) void k_conv8(
    const u16* __restrict__ st, const u16* __restrict__ wt, u16* __restrict__ out,
    int H2, int W2, int ktot, int nsplit) {
  __shared__ __align__(16) char smem[131072];   // 2 bufs x (A 32K + B 32K)
  const int t = threadIdx.x;
  const int lane = t & 63;
  const int wv = t >> 6;
  const int wm = wv >> 2, wn = wv & 3;          // 2M x 4N waves; wave tile 128x64
  const int nwg = gridDim.x;
  const int bid = blockIdx.x;
  const int lb = (bid & 7) * (nwg >> 3) + (bid >> 3);  // XCD-chunked (nwg%8==0)
  const int m0 = lb * 256;
  const int PW = W2 + 4;
  const int spl = blockIdx.y;
  const int kk0 = (spl * ktot) / nsplit;
  const int kk1 = ((spl + 1) * ktot) / nsplit;
  const long Mrows = (long)nwg * 256;
  u16* yo = out + (long)spl * Mrows * 256;

  const int trow = t >> 3;
  const int srcci = ((t & 7) ^ (trow & 7)) * 8;
  const char* baseA[4];
#pragma unroll
  for (int u = 0; u < 4; ++u) {
    int m = m0 + u * 64 + trow;
    int w = m % W2; int q = m / W2;
    int hh = q % H2; int b = q / H2;
    long sp = ((long)(b * (H2 + 4) + hh + 2) * PW + (w + 2));
    baseA[u] = (const char*)(st + sp * 256 + srcci);
  }
  const char* baseB0 = (const char*)(wt + trow * 256 + srcci);

  f32x4 acc[8][4];
#pragma unroll
  for (int i = 0; i < 8; ++i)
#pragma unroll
    for (int j = 0; j < 4; ++j) acc[i][j] = f32x4{0.f, 0.f, 0.f, 0.f};

  const int kq = (lane >> 4) * 16;
  const int sw = (lane & 7) << 4;
  int va0 = (wm * 128 + (lane & 15)) * 128 + (kq ^ sw);
  int va1 = (wm * 128 + (lane & 15)) * 128 + ((64 + kq) ^ sw);
  int vb0 = 32768 + (wn * 64 + (lane & 15)) * 128 + (kq ^ sw);
  int vb1 = 32768 + (wn * 64 + (lane & 15)) * 128 + ((64 + kq) ^ sw);

  bf16x8 a0[4][2], a1[4][2], b0[2][2], b1[2][2];

  auto offsets = [&](int kk, long& oA, long& oB) {
    int tap = kk >> 2, cic = kk & 3;
    int dy = tap / 5 - 2, dx = tap % 5 - 2;
    oA = ((long)(dy * PW + dx) * 256 + cic * 64) * 2;
    oB = ((long)tap * 65536 + cic * 64) * 2;
  };
  auto stageA4 = [&](long off, int dsto) {
    char* d = smem + dsto + wv * 1024;
#pragma unroll
    for (int u = 0; u < 4; ++u) gload16(baseA[u] + off, d + u * 8192);
  };
  auto stageB4 = [&](long off, int dsto) {
    char* d = smem + dsto + 32768 + wv * 1024;
#pragma unroll
    for (int u = 0; u < 4; ++u) gload16(baseB0 + u * 32768 + off, d + u * 8192);
  };

#define LDA0 { _Pragma("unroll") for (int i = 0; i < 4; ++i) {       \
    a0[i][0] = *(const bf16x8*)(smem + va0 + i * 2048);              \
    a0[i][1] = *(const bf16x8*)(smem + va1 + i * 2048); } }
#define LDA1 { _Pragma("unroll") for (int i = 0; i < 4; ++i) {       \
    a1[i][0] = *(const bf16x8*)(smem + va0 + 8192 + i * 2048);       \
    a1[i][1] = *(const bf16x8*)(smem + va1 + 8192 + i * 2048); } }
#define LDB0 { _Pragma("unroll") for (int j = 0; j < 2; ++j) {       \
    b0[j][0] = *(const bf16x8*)(smem + vb0 + j * 2048);              \
    b0[j][1] = *(const bf16x8*)(smem + vb1 + j * 2048); } }
#define LDB1 { _Pragma("unroll") for (int j = 0; j < 2; ++j) {       \
    b1[j][0] = *(const bf16x8*)(smem + vb0 + 4096 + j * 2048);       \
    b1[j][1] = *(const bf16x8*)(smem + vb1 + 4096 + j * 2048); } }
#define MMQ(A, B, IB, JB)                                                     \
  _Pragma("unroll") for (int i = 0; i < 4; ++i)                               \
  _Pragma("unroll") for (int j = 0; j < 2; ++j)                               \
  _Pragma("unroll") for (int k = 0; k < 2; ++k)                               \
    acc[(IB) + i][(JB) + j] = __builtin_amdgcn_mfma_f32_16x16x32_bf16(        \
        A[i][k], B[j][k], acc[(IB) + i][(JB) + j], 0, 0, 0);

  long oA, oB;
  offsets(kk0, oA, oB);
  stageA4(oA, 0); stageB4(oB, 0);
  offsets(kk0 + 1, oA, oB);
  stageA4(oA, 65536); stageB4(oB, 65536);
  asm volatile("s_waitcnt vmcnt(8)" ::: "memory");
  __builtin_amdgcn_s_barrier();
  LDA0 LDB0

  int curo = 0;
  for (int kt = kk0; kt < kk1; ++kt) {
    const bool stg = (kt + 2) < kk1;
    const bool rd1 = (kt + 1) < kk1;
    LDA1 LDB1
    va0 ^= 65536; va1 ^= 65536; vb0 ^= 65536; vb1 ^= 65536;
    __builtin_amdgcn_s_barrier();
    asm volatile("s_waitcnt lgkmcnt(12)" ::: "memory");
    __builtin_amdgcn_sched_barrier(0);
    __builtin_amdgcn_s_setprio(1);
    MMQ(a0, b0, 0, 0)
    __builtin_amdgcn_s_setprio(0);
    __builtin_amdgcn_s_barrier();
    asm volatile("s_waitcnt lgkmcnt(4)" ::: "memory");
    __builtin_amdgcn_sched_barrier(0);
    __builtin_amdgcn_s_setprio(1);
    MMQ(a1, b0, 4, 0)
    __builtin_amdgcn_s_setprio(0);
    if (rd1) { asm volatile("s_waitcnt vmcnt(0)" ::: "memory"); }
    __builtin_amdgcn_s_barrier();
    asm volatile("s_waitcnt lgkmcnt(0)" ::: "memory");
    __builtin_amdgcn_sched_barrier(0);
    __builtin_amdgcn_s_setprio(1);
    MMQ(a1, b1, 4, 2)
    __builtin_amdgcn_s_setprio(0);
    if (rd1) { LDB0 }
    if (stg) { offsets(kt + 2, oA, oB); stageA4(oA, curo); }
    __builtin_amdgcn_s_barrier();
    __builtin_amdgcn_s_setprio(1);
    MMQ(a0, b1, 0, 2)
    __builtin_amdgcn_s_setprio(0);
    if (stg) { stageB4(oB, curo); }
    if (rd1) { LDA0 }
    curo ^= 65536;
  }
#undef MMQ
#undef LDA0
#undef LDA1
#undef LDB0
#undef LDB1

#pragma unroll
  for (int i = 0; i < 8; ++i) {
    int mloc = m0 + wm * 128 + i * 16 + (lane >> 4) * 4;
#pragma unroll
    for (int j = 0; j < 4; ++j) {
      int nloc = wn * 64 + j * 16 + (lane & 15);
#pragma unroll
      for (int r = 0; r < 4; ++r)
        yo[(long)(mloc + r) * 256 + nloc] = f2bf(acc[i][j][r]);
    }
  }
}

// ---------------- IDWT with fused K-split partial reduce ----------------
// P: ns partials, each [B,H2,W2,256] bf16; (+next_ll fp32 NCHW) -> out fp32 NCHW.
__global__ void k_idwt(const u16* __restrict__ P, long psz, int ns,
                       const float* __restrict__ nll, const float* __restrict__ bias,
                       float* __restrict__ out, int B_, int H2, int W2) {
  int idx = blockIdx.x * blockDim.x + threadIdx.x;
  int W2h = W2 >> 1;
  int total = B_ * 64 * H2 * W2h;
  if (idx >= total) return;
  int w2h = idx % W2h; int t2 = idx / W2h;
  int h2 = t2 % H2; t2 /= H2;
  int c = t2 % 64; int b = t2 / 64;
  int w2 = w2h * 2;
  long ybase = (((long)b * H2 + h2) * W2 + w2) * 256 + 4 * c;
  float s[8] = {0.f, 0.f, 0.f, 0.f, 0.f, 0.f, 0.f, 0.f};
  for (int k = 0; k < ns; ++k) {
    const u16* p = P + (long)k * psz + ybase;
    ushort4 q0 = *(const ushort4*)(p);
    ushort4 q1 = *(const ushort4*)(p + 256);
    s[0] += bf2f(q0.x); s[1] += bf2f(q0.y); s[2] += bf2f(q0.z); s[3] += bf2f(q0.w);
    s[4] += bf2f(q1.x); s[5] += bf2f(q1.y); s[6] += bf2f(q1.z); s[7] += bf2f(q1.w);
  }
  float llv0 = s[0], lh0 = s[1], hl0 = s[2], hh0 = s[3];
  float llv1 = s[4], lh1 = s[5], hl1 = s[6], hh1 = s[7];
  if (nll) {
    float2 nv = *(const float2*)(nll + (((long)(b * 64 + c) * H2 + h2) * W2 + w2));
    llv0 += nv.x; llv1 += nv.y;
  }
  float bv = bias ? bias[c] : 0.f;
  float a0 = 0.5f * (llv0 + lh0 + hl0 + hh0) + bv;
  float b0 = 0.5f * (llv0 + lh0 - hl0 - hh0) + bv;
  float c0 = 0.5f * (llv0 - lh0 + hl0 - hh0) + bv;
  float d0 = 0.5f * (llv0 - lh0 - hl0 + hh0) + bv;
  float a1 = 0.5f * (llv1 + lh1 + hl1 + hh1) + bv;
  float b1 = 0.5f * (llv1 + lh1 - hl1 - hh1) + bv;
  float c1 = 0.5f * (llv1 - lh1 + hl1 - hh1) + bv;
  float d1 = 0.5f * (llv1 - lh1 - hl1 + hh1) + bv;
  long obase = (((long)(b * 64 + c) * (2 * H2) + 2 * h2) * (2 * W2)) + 2 * w2;
  *(float4*)(out + obase)          = make_float4(a0, b0, a1, b1);
  *(float4*)(out + obase + 2 * W2) = make_float4(c0, d0, c1, d1);
}

// ---------------- workspace layout (bytes) ----------------
constexpr size_t WBF_SZ1 = 25ull * 256 * 256 * 2;             // 3,276,800
constexpr size_t OFF_WBF = 0;
constexpr size_t OFF_S0  = 3 * WBF_SZ1;                       // 9,830,400
constexpr size_t S0_SZ   = 8ull * 132 * 132 * 256 * 2;        // 71,368,704
constexpr size_t OFF_L0  = OFF_S0 + S0_SZ;                    // l0 33.5MB; later P1
constexpr size_t OFF_Y0  = OFF_L0 + 8ull * 64 * 128 * 128 * 4;// y0 67MB
// inside S0 (read/write sets disjoint per dispatch; s1/s2 borders zeroed AFTER conv0):
constexpr size_t REL_S1 = 0;                                  // s1 19.0MB (dwt1->conv1)
constexpr size_t REL_L1 = 8ull * 68 * 68 * 256 * 2;           // 18,939,904: l1 8.4MB (dwt1->dwt2)
constexpr size_t REL_S2 = REL_L1 + 8ull * 64 * 64 * 64 * 4;   // 27,328,512: s2 5.3MB (dwt2->conv2)
constexpr size_t REL_P2 = REL_S2 + 8ull * 36 * 36 * 256 * 2;  // 32,636,928: P2 33.5MB (conv2->idwt2)
constexpr size_t REL_N2 = 0;                                  // n2 8.4MB (idwt2->idwt1); over dead s1/l2
constexpr size_t REL_N1 = 8ull * 64 * 64 * 64 * 4;            // 8,388,608: n1 33.5MB (idwt1->idwt0)
constexpr size_t REL_L2 = 0;                                  // l2 2.1MB scratch (never read; over dead s1)

extern "C" void kernel_launch(void* const* d_in, const int* in_sizes, int n_in,
                              void* d_out, int out_size, void* d_ws, size_t ws_size,
                              hipStream_t stream) {
  const float* x    = (const float*)d_in[0];
  const float* w0   = (const float*)d_in[1];
  const float* w1   = (const float*)d_in[2];
  const float* w2   = (const float*)d_in[3];
  const float* bias = (const float*)d_in[4];
  float* out = (float*)d_out;
  char* ws = (char*)d_ws;

  u16* wbf0 = (u16*)(ws + OFF_WBF);
  u16* wbf1 = (u16*)(ws + OFF_WBF + WBF_SZ1);
  u16* wbf2 = (u16*)(ws + OFF_WBF + 2 * WBF_SZ1);
  u16* s0   = (u16*)(ws + OFF_S0);
  u16* s1   = (u16*)(ws + OFF_S0 + REL_S1);
  float* l1 = (float*)(ws + OFF_S0 + REL_L1);
  u16* s2   = (u16*)(ws + OFF_S0 + REL_S2);
  u16* P2   = (u16*)(ws + OFF_S0 + REL_P2);
  float* n2 = (float*)(ws + OFF_S0 + REL_N2);
  float* n1 = (float*)(ws + OFF_S0 + REL_N1);
  float* l2 = (float*)(ws + OFF_S0 + REL_L2);
  float* l0 = (float*)(ws + OFF_L0);
  u16* P1   = (u16*)(ws + OFF_L0);     // aliases l0 (dead after dwt1)
  u16* y0   = (u16*)(ws + OFF_Y0);

  k_wtrans3<<<dim3(256, 3), 256, 0, stream>>>(w0, w1, w2, wbf0, wbf1, wbf2);

  // level 0 (s0 border first; dwt writes interior only)
  k_border<<<2080, 256, 0, stream>>>(s0, 8, 128, 128);
  k_dwt<<<16384, 256, 0, stream>>>(x, s0, l0, 8, 128, 128);
  k_conv8<<<dim3(512, 1), 512, 0, stream>>>(s0, wbf0, y0, 128, 128, 100, 1);

  // s1/s2 borders AFTER conv0 — dwt0 wrote the whole S0 region (incl. these sub-buffers)
  k_border<<<1056, 256, 0, stream>>>(s1, 8, 64, 64);
  k_border<<<544, 256, 0, stream>>>(s2, 8, 32, 32);

  // level 1 (K-split 2 -> P1)
  k_dwt<<<4096, 256, 0, stream>>>(l0, s1, l1, 8, 64, 64);
  k_conv8<<<dim3(128, 2), 512, 0, stream>>>(s1, wbf1, P1, 64, 64, 100, 2);

  // level 2 (K-split 8 -> P2); l2 scratch over dead s1 (after conv1)
  k_dwt<<<1024, 256, 0, stream>>>(l1, s2, l2, 8, 32, 32);
  k_conv8<<<dim3(32, 8), 512, 0, stream>>>(s2, wbf2, P2, 32, 32, 100, 8);

  // reconstruction (idwt fuses the partial reduce)
  k_idwt<<<1024, 256, 0, stream>>>(P2, 2097152L, 8, nullptr, nullptr, n2, 8, 32, 32);
  k_idwt<<<4096, 256, 0, stream>>>(P1, 8388608L, 2, n2, nullptr, n1, 8, 64, 64);
  k_idwt<<<16384, 256, 0, stream>>>(y0, 33554432L, 1, n1, bias, out, 8, 128, 128);
}